// Round 2
// baseline (329.604 us; speedup 1.0000x reference)
//
#include <hip/hip_runtime.h>

typedef unsigned short u16;
typedef __attribute__((ext_vector_type(4))) float f32x4;
typedef __attribute__((ext_vector_type(8))) _Float16 f16x8;
typedef __attribute__((ext_vector_type(8))) unsigned short u16x8;
typedef __attribute__((ext_vector_type(4))) unsigned short u16x4;

#define DEV __device__ __forceinline__

// ---------- helpers ----------
DEV u16 f2h(float f) {  // fp32 -> fp16 (RNE)
    _Float16 h = (_Float16)f;
    u16 r;
    __builtin_memcpy(&r, &h, 2);
    return r;
}

DEV f32x4 mfma16(f16x8 a, f16x8 b, f32x4 c) {
    return __builtin_amdgcn_mfma_f32_16x16x32_f16(a, b, c, 0, 0, 0);
}

DEV void gload16(const void* g, void* l) {
    __builtin_amdgcn_global_load_lds(
        (const __attribute__((address_space(1))) void*)g,
        (__attribute__((address_space(3))) void*)l, 16, 0, 0);
}

// ---------- problem constants ----------
#define BB 4
#define NN 4096
#define CC 512
#define CI 256
#define RR (BB * NN)  // 16384

// ---------- workspace layout (bytes) ----------
#define OFF_FEAT 0u                     // 16384*512*2 = 16,777,216
#define OFF_Q    16777216u              // 8,388,608
#define OFF_K    25165824u
#define OFF_V    33554432u
#define OFF_Y    41943040u
#define OFF_WQKV 50331648u              // 768*512*2 = 786,432
#define OFF_WO   51118080u              // 512*256*2 = 262,144
#define OFF_BQKV 51380224u              // 768*4
#define OFF_PART 51383296u              // 128*1024*4 = 524,288
#define OFF_SS   51907584u              // 1024*4 (scale, shift)

// ============ BN stats ============
__global__ void bn_partial(const float* __restrict__ x, float* __restrict__ part) {
    // grid 128, block 512: block handles 128 rows, thread = channel
    const int c = threadIdx.x;
    const int blk = blockIdx.x;
    const float* xp = x + (size_t)blk * 128 * CC + c;
    float s = 0.f, q = 0.f;
    for (int r = 0; r < 128; r++) {
        float v = xp[(size_t)r * CC];
        s += v; q += v * v;
    }
    part[blk * 1024 + c] = s;
    part[blk * 1024 + 512 + c] = q;
}

__global__ void bn_final(const float* __restrict__ part,
                         const float* __restrict__ gamma, const float* __restrict__ beta,
                         float* __restrict__ ss) {
    const int c = threadIdx.x;  // 512 threads
    float s = 0.f, q = 0.f;
    for (int i = 0; i < 128; i++) {
        s += part[i * 1024 + c];
        q += part[i * 1024 + 512 + c];
    }
    float m = s * (1.0f / (float)RR);
    float var = q * (1.0f / (float)RR) - m * m;
    float istd = rsqrtf(var + 1e-5f);
    float g = gamma[c] * istd;
    ss[c] = g;                      // scale
    ss[512 + c] = beta[c] - m * g;  // shift
}

// ============ weight conversion ============
__global__ void cvt_weights(const float* __restrict__ thw, const float* __restrict__ phw,
                            const float* __restrict__ gw,
                            const float* __restrict__ thb, const float* __restrict__ phb,
                            const float* __restrict__ gb,
                            const float* __restrict__ ww,
                            u16* __restrict__ wqkv, u16* __restrict__ wo,
                            float* __restrict__ bqkv) {
    const int idx = blockIdx.x * 256 + threadIdx.x;
    if (idx < 768 * 512) {
        int row = idx >> 9, col = idx & 511;
        float v = (row < 256) ? thw[row * 512 + col]
                : (row < 512) ? phw[(row - 256) * 512 + col]
                              : gw[(row - 512) * 512 + col];
        wqkv[idx] = f2h(v);
    } else if (idx < 768 * 512 + 512 * 256) {
        int j = idx - 768 * 512;
        wo[j] = f2h(ww[j]);
    }
    if (idx < 768) {
        bqkv[idx] = (idx < 256) ? thb[idx] : (idx < 512) ? phb[idx - 256] : gb[idx - 512];
    }
}

// ============ BN apply + ReLU -> fp16 ============
__global__ void feat_kernel(const float* __restrict__ x, const float* __restrict__ ss,
                            u16* __restrict__ feat) {
    const int total = RR * CC / 4;
    for (int idx = blockIdx.x * blockDim.x + threadIdx.x; idx < total;
         idx += gridDim.x * blockDim.x) {
        f32x4 xv = ((const f32x4*)x)[idx];
        int c4 = idx & 127;  // which group of 4 channels
        f32x4 sc = ((const f32x4*)ss)[c4];
        f32x4 sh = ((const f32x4*)(ss + 512))[c4];
        u16x4 o;
        #pragma unroll
        for (int e = 0; e < 4; e++) {
            float f = fmaxf(xv[e] * sc[e] + sh[e], 0.f);
            o[e] = f2h(f);
        }
        ((u16x4*)feat)[idx] = o;
    }
}

// ============ GEMM (A: MxK fp16 row-major, Bm: NxK fp16 row-major) ============
// MODE 0: out = A*B^T + bias -> fp16, scattered to q/k/v buffers (N=768)
// MODE 1: out = x + A*B^T + bias -> fp32 (N=512)
template <int MODE>
__global__ __launch_bounds__(256) void gemm_bt(
    const u16* __restrict__ A, const u16* __restrict__ Bm, int K,
    const float* __restrict__ bias, const float* __restrict__ xres,
    u16* __restrict__ oq, u16* __restrict__ okk, u16* __restrict__ ov,
    float* __restrict__ of) {
    __shared__ u16 As[128 * 32];
    __shared__ u16 Bs[128 * 32];
    const int tid = threadIdx.x;
    const int lane = tid & 63;
    const int l15 = lane & 15, kg = lane >> 4;
    const int wv = tid >> 6;
    const int wm = wv >> 1, wn = wv & 1;
    const int m0 = blockIdx.x * 128, n0 = blockIdx.y * 128;

    f32x4 acc[4][4];
    #pragma unroll
    for (int i = 0; i < 4; i++)
        #pragma unroll
        for (int j = 0; j < 4; j++) acc[i][j] = (f32x4){0.f, 0.f, 0.f, 0.f};

    const int rowA = tid >> 2, colA = (tid & 3) * 8;
    for (int k0 = 0; k0 < K; k0 += 32) {
        gload16(A + (size_t)(m0 + rowA) * K + k0 + colA, &As[tid * 8]);
        gload16(A + (size_t)(m0 + 64 + rowA) * K + k0 + colA, &As[2048 + tid * 8]);
        gload16(Bm + (size_t)(n0 + rowA) * K + k0 + colA, &Bs[tid * 8]);
        gload16(Bm + (size_t)(n0 + 64 + rowA) * K + k0 + colA, &Bs[2048 + tid * 8]);
        __syncthreads();
        f16x8 af[4], bfr[4];
        #pragma unroll
        for (int i = 0; i < 4; i++)
            af[i] = *(const f16x8*)&As[(wm * 64 + i * 16 + l15) * 32 + kg * 8];
        #pragma unroll
        for (int i = 0; i < 4; i++)
            bfr[i] = *(const f16x8*)&Bs[(wn * 64 + i * 16 + l15) * 32 + kg * 8];
        #pragma unroll
        for (int mi = 0; mi < 4; mi++)
            #pragma unroll
            for (int ni = 0; ni < 4; ni++)
                acc[mi][ni] = mfma16(af[mi], bfr[ni], acc[mi][ni]);
        __syncthreads();
    }

    // epilogue: C/D layout col = lane&15, row = (lane>>4)*4 + r
    #pragma unroll
    for (int mi = 0; mi < 4; mi++) {
        #pragma unroll
        for (int ni = 0; ni < 4; ni++) {
            #pragma unroll
            for (int r = 0; r < 4; r++) {
                int row = m0 + wm * 64 + mi * 16 + kg * 4 + r;
                int col = n0 + wn * 64 + ni * 16 + l15;
                float v = acc[mi][ni][r];
                if constexpr (MODE == 0) {
                    v += bias[col];
                    u16* dst = (n0 < 256) ? oq : (n0 < 512) ? okk : ov;
                    dst[(size_t)row * 256 + (col & 255)] = f2h(v);
                } else {
                    size_t o = (size_t)row * 512 + col;
                    of[o] = xres[o] + v + bias[col];
                }
            }
        }
    }
}

// ============ flash attention ============
// grid 256 = 4 batches x 64 q-tiles of 64 rows; block 256 = 4 waves x 16 q-rows
// LDS: Ks [64][256] swizzled (32KB) | Vt [256][64] swizzled (32KB) | Ps [4][16][72] (9KB)
#define ATTN_LDS (64 * 256 * 2 + 256 * 64 * 2 + 4 * 16 * 72 * 2)

__global__ __launch_bounds__(256) void attn_kernel(
    const u16* __restrict__ Qg, const u16* __restrict__ Kg,
    const u16* __restrict__ Vg, u16* __restrict__ Yg) {
    extern __shared__ u16 smem[];
    u16* Ks = smem;            // 16384 elems
    u16* Vt = smem + 16384;    // 16384 elems
    u16* Ps = smem + 32768;    // 4608 elems

    const int tid = threadIdx.x, lane = tid & 63, wv = tid >> 6;
    const int l15 = lane & 15, kg = lane >> 4;
    const int b = blockIdx.x >> 6, qt = blockIdx.x & 63;
    const size_t kvbase = (size_t)b * NN * CI;

    // Q fragments in registers: row = wv*16 + l15, k = kk*32 + kg*8 + j
    f16x8 qf[8];
    {
        const u16* qp = Qg + ((size_t)b * NN + qt * 64 + wv * 16 + l15) * CI + kg * 8;
        #pragma unroll
        for (int kk = 0; kk < 8; kk++) qf[kk] = *(const f16x8*)(qp + kk * 32);
    }

    f32x4 acc[16];
    #pragma unroll
    for (int i = 0; i < 16; i++) acc[i] = (f32x4){0.f, 0.f, 0.f, 0.f};
    float mrow[4], lrow[4];
    #pragma unroll
    for (int r = 0; r < 4; r++) { mrow[r] = -1e30f; lrow[r] = 0.f; }

    u16* Psw = Ps + wv * 1152;

    for (int kv0 = 0; kv0 < NN; kv0 += 64) {
        // ---- stage K, swizzled: elem(row,c) = row*256 + ((c>>3 ^ (row&7))<<3) + (c&7)
        {
            int chunk = tid & 31, rb = tid >> 5;
            #pragma unroll
            for (int i = 0; i < 8; i++) {
                int row = i * 8 + rb;
                int sc = chunk ^ (row & 7);
                gload16(Kg + kvbase + (size_t)(kv0 + row) * CI + sc * 8,
                        &Ks[row * 256 + chunk * 8]);
            }
        }
        // ---- stage V transposed+swizzled: Vt elem(d,key) = d*64 + (((key>>3)^(d&7))<<3) + (key&7)
        {
            const u16* vp = Vg + kvbase + (size_t)(kv0 + lane) * CI + wv * 64;
            #pragma unroll
            for (int dd = 0; dd < 8; dd++) {
                u16x8 vvv = *(const u16x8*)(vp + dd * 8);
                #pragma unroll
                for (int e = 0; e < 8; e++) {
                    int d = wv * 64 + dd * 8 + e;
                    Vt[d * 64 + (((lane >> 3) ^ (d & 7)) << 3) + (lane & 7)] = vvv[e];
                }
            }
        }
        __syncthreads();

        // ---- S = Q K^T (16 rows x 64 keys per wave)
        f32x4 s[4];
        #pragma unroll
        for (int nt = 0; nt < 4; nt++) s[nt] = (f32x4){0.f, 0.f, 0.f, 0.f};
        #pragma unroll
        for (int kk = 0; kk < 8; kk++) {
            #pragma unroll
            for (int nt = 0; nt < 4; nt++) {
                int krow = nt * 16 + l15;
                f16x8 bk = *(const f16x8*)&Ks[krow * 256 + (((kk * 4 + kg) ^ (krow & 7)) << 3)];
                s[nt] = mfma16(qf[kk], bk, s[nt]);
            }
        }

        // ---- online softmax (rows kg*4+r; cols across the 16 lanes of the group)
        float scl[4];
        #pragma unroll
        for (int r = 0; r < 4; r++) {
            float mx = fmaxf(fmaxf(s[0][r], s[1][r]), fmaxf(s[2][r], s[3][r]));
            mx = fmaxf(mx, __shfl_xor(mx, 1));
            mx = fmaxf(mx, __shfl_xor(mx, 2));
            mx = fmaxf(mx, __shfl_xor(mx, 4));
            mx = fmaxf(mx, __shfl_xor(mx, 8));
            float mnew = fmaxf(mrow[r], mx);
            scl[r] = __expf(mrow[r] - mnew);
            mrow[r] = mnew;
        }
        float rs[4] = {0.f, 0.f, 0.f, 0.f};
        #pragma unroll
        for (int nt = 0; nt < 4; nt++)
            #pragma unroll
            for (int r = 0; r < 4; r++) {
                float p = __expf(s[nt][r] - mrow[r]);
                s[nt][r] = p;
                rs[r] += p;
            }
        #pragma unroll
        for (int r = 0; r < 4; r++) {
            rs[r] += __shfl_xor(rs[r], 1);
            rs[r] += __shfl_xor(rs[r], 2);
            rs[r] += __shfl_xor(rs[r], 4);
            rs[r] += __shfl_xor(rs[r], 8);
            lrow[r] = lrow[r] * scl[r] + rs[r];
        }
        #pragma unroll
        for (int i = 0; i < 16; i++)
            #pragma unroll
            for (int r = 0; r < 4; r++) acc[i][r] *= scl[r];

        // ---- P -> LDS (fp16), layout [qrow][key] stride 72
        #pragma unroll
        for (int nt = 0; nt < 4; nt++)
            #pragma unroll
            for (int r = 0; r < 4; r++)
                Psw[(kg * 4 + r) * 72 + nt * 16 + l15] = f2h(s[nt][r]);

        // ---- PV: acc += P(16x64) * V(64x256)
        #pragma unroll
        for (int kk2 = 0; kk2 < 2; kk2++) {
            f16x8 pa = *(const f16x8*)&Psw[l15 * 72 + kk2 * 32 + kg * 8];
            #pragma unroll
            for (int dt = 0; dt < 16; dt++) {
                int d = dt * 16 + l15;
                f16x8 bv = *(const f16x8*)&Vt[d * 64 + (((kk2 * 4 + kg) ^ (d & 7)) << 3)];
                acc[dt] = mfma16(pa, bv, acc[dt]);
            }
        }
        __syncthreads();
    }

    // ---- write Y (fp16)
    const size_t orow0 = (size_t)b * NN + qt * 64 + wv * 16;
    #pragma unroll
    for (int dt = 0; dt < 16; dt++)
        #pragma unroll
        for (int r = 0; r < 4; r++) {
            float o = acc[dt][r] / lrow[r];
            Yg[(orow0 + kg * 4 + r) * CI + dt * 16 + l15] = f2h(o);
        }
}

// ============ launcher ============
extern "C" void kernel_launch(void* const* d_in, const int* in_sizes, int n_in,
                              void* d_out, int out_size, void* d_ws, size_t ws_size,
                              hipStream_t stream) {
    (void)in_sizes; (void)n_in; (void)out_size; (void)ws_size;
    const float* x     = (const float*)d_in[0];
    const float* gamma = (const float*)d_in[1];
    const float* beta  = (const float*)d_in[2];
    const float* thw   = (const float*)d_in[3];
    const float* thb   = (const float*)d_in[4];
    const float* phw   = (const float*)d_in[5];
    const float* phb   = (const float*)d_in[6];
    const float* gw    = (const float*)d_in[7];
    const float* gb    = (const float*)d_in[8];
    const float* ww    = (const float*)d_in[9];
    const float* wb    = (const float*)d_in[10];

    char* ws = (char*)d_ws;
    u16* feat  = (u16*)(ws + OFF_FEAT);
    u16* qb    = (u16*)(ws + OFF_Q);
    u16* kb    = (u16*)(ws + OFF_K);
    u16* vb    = (u16*)(ws + OFF_V);
    u16* yb    = (u16*)(ws + OFF_Y);
    u16* wqkv  = (u16*)(ws + OFF_WQKV);
    u16* wo    = (u16*)(ws + OFF_WO);
    float* bqkv = (float*)(ws + OFF_BQKV);
    float* part = (float*)(ws + OFF_PART);
    float* ss   = (float*)(ws + OFF_SS);
    float* out  = (float*)d_out;

    hipFuncSetAttribute((const void*)attn_kernel,
                        hipFuncAttributeMaxDynamicSharedMemorySize, ATTN_LDS);

    bn_partial<<<128, 512, 0, stream>>>(x, part);
    bn_final<<<1, 512, 0, stream>>>(part, gamma, beta, ss);
    cvt_weights<<<2048, 256, 0, stream>>>(thw, phw, gw, thb, phb, gb, ww, wqkv, wo, bqkv);
    feat_kernel<<<2048, 256, 0, stream>>>(x, ss, feat);
    gemm_bt<0><<<dim3(128, 6), 256, 0, stream>>>(feat, wqkv, 512, bqkv, nullptr,
                                                 qb, kb, vb, nullptr);
    attn_kernel<<<256, 256, ATTN_LDS, stream>>>(qb, kb, vb, yb);
    gemm_bt<1><<<dim3(128, 4), 256, 0, stream>>>(yb, wo, 256, wb, x,
                                                 nullptr, nullptr, nullptr, out);
}

// Round 4
// 247.365 us; speedup vs baseline: 1.3325x; 1.3325x over previous
//
#include <hip/hip_runtime.h>

typedef unsigned short u16;
typedef __attribute__((ext_vector_type(4))) float f32x4;
typedef __attribute__((ext_vector_type(8))) _Float16 f16x8;
typedef __attribute__((ext_vector_type(8))) unsigned short u16x8;
typedef __attribute__((ext_vector_type(4))) unsigned short u16x4;

#define DEV __device__ __forceinline__

// ---------- helpers ----------
DEV u16 f2h(float f) {  // fp32 -> fp16 (RNE)
    _Float16 h = (_Float16)f;
    u16 r;
    __builtin_memcpy(&r, &h, 2);
    return r;
}

DEV f32x4 mfma16(f16x8 a, f16x8 b, f32x4 c) {
    return __builtin_amdgcn_mfma_f32_16x16x32_f16(a, b, c, 0, 0, 0);
}

DEV void gload16(const void* g, void* l) {
    __builtin_amdgcn_global_load_lds(
        (const __attribute__((address_space(1))) void*)g,
        (__attribute__((address_space(3))) void*)l, 16, 0, 0);
}

// ---------- problem constants ----------
#define BB 4
#define NN 4096
#define CC 512
#define CI 256
#define RR (BB * NN)  // 16384

// ---------- workspace layout (bytes) ----------
#define OFF_FEAT 0u                     // 16384*512*2 = 16,777,216
#define OFF_Q    16777216u              // 8,388,608
#define OFF_K    25165824u
#define OFF_V    33554432u              // V^T layout [b][d][key]
#define OFF_Y    41943040u
#define OFF_WQKV 50331648u              // 768*512*2 = 786,432
#define OFF_WO   51118080u              // 512*256*2 = 262,144
#define OFF_BQKV 51380224u              // 768*4
#define OFF_PART 51383296u              // 128*1024*4 = 524,288
#define OFF_SS   51907584u              // 1024*4 (scale, shift)

// ============ BN stats ============
__global__ void bn_partial(const float* __restrict__ x, float* __restrict__ part) {
    const int c = threadIdx.x;
    const int blk = blockIdx.x;
    const float* xp = x + (size_t)blk * 128 * CC + c;
    float s = 0.f, q = 0.f;
    for (int r = 0; r < 128; r++) {
        float v = xp[(size_t)r * CC];
        s += v; q += v * v;
    }
    part[blk * 1024 + c] = s;
    part[blk * 1024 + 512 + c] = q;
}

__global__ void bn_final(const float* __restrict__ part,
                         const float* __restrict__ gamma, const float* __restrict__ beta,
                         float* __restrict__ ss) {
    const int c = threadIdx.x;  // 512 threads
    float s = 0.f, q = 0.f;
    for (int i = 0; i < 128; i++) {
        s += part[i * 1024 + c];
        q += part[i * 1024 + 512 + c];
    }
    float m = s * (1.0f / (float)RR);
    float var = q * (1.0f / (float)RR) - m * m;
    float istd = rsqrtf(var + 1e-5f);
    float g = gamma[c] * istd;
    ss[c] = g;                      // scale
    ss[512 + c] = beta[c] - m * g;  // shift
}

// ============ weight conversion ============
__global__ void cvt_weights(const float* __restrict__ thw, const float* __restrict__ phw,
                            const float* __restrict__ gw,
                            const float* __restrict__ thb, const float* __restrict__ phb,
                            const float* __restrict__ gb,
                            const float* __restrict__ ww,
                            u16* __restrict__ wqkv, u16* __restrict__ wo,
                            float* __restrict__ bqkv) {
    const int idx = blockIdx.x * 256 + threadIdx.x;
    if (idx < 768 * 512) {
        int row = idx >> 9, col = idx & 511;
        float v = (row < 256) ? thw[row * 512 + col]
                : (row < 512) ? phw[(row - 256) * 512 + col]
                              : gw[(row - 512) * 512 + col];
        wqkv[idx] = f2h(v);
    } else if (idx < 768 * 512 + 512 * 256) {
        int j = idx - 768 * 512;
        wo[j] = f2h(ww[j]);
    }
    if (idx < 768) {
        bqkv[idx] = (idx < 256) ? thb[idx] : (idx < 512) ? phb[idx - 256] : gb[idx - 512];
    }
}

// ============ BN apply + ReLU -> fp16 ============
__global__ void feat_kernel(const float* __restrict__ x, const float* __restrict__ ss,
                            u16* __restrict__ feat) {
    const int total = RR * CC / 4;
    for (int idx = blockIdx.x * blockDim.x + threadIdx.x; idx < total;
         idx += gridDim.x * blockDim.x) {
        f32x4 xv = ((const f32x4*)x)[idx];
        int c4 = idx & 127;
        f32x4 sc = ((const f32x4*)ss)[c4];
        f32x4 sh = ((const f32x4*)(ss + 512))[c4];
        u16x4 o;
        #pragma unroll
        for (int e = 0; e < 4; e++) {
            float f = fmaxf(xv[e] * sc[e] + sh[e], 0.f);
            o[e] = f2h(f);
        }
        ((u16x4*)feat)[idx] = o;
    }
}

// ============ GEMM (A: MxK fp16 row-major, Bm: NxK fp16 row-major) ============
// MODE 0: out = A*B^T + bias -> fp16; Q,K row-major [token][d], V TRANSPOSED [b][d][key]
// MODE 1: out = x + A*B^T + bias -> fp32 (N=512)
template <int MODE>
__global__ __launch_bounds__(256) void gemm_bt(
    const u16* __restrict__ A, const u16* __restrict__ Bm, int K,
    const float* __restrict__ bias, const float* __restrict__ xres,
    u16* __restrict__ oq, u16* __restrict__ okk, u16* __restrict__ ov,
    float* __restrict__ of) {
    __shared__ u16 As[128 * 32];
    __shared__ u16 Bs[128 * 32];
    const int tid = threadIdx.x;
    const int lane = tid & 63;
    const int l15 = lane & 15, kg = lane >> 4;
    const int wv = tid >> 6;
    const int wm = wv >> 1, wn = wv & 1;
    const int m0 = blockIdx.x * 128, n0 = blockIdx.y * 128;

    f32x4 acc[4][4];
    #pragma unroll
    for (int i = 0; i < 4; i++)
        #pragma unroll
        for (int j = 0; j < 4; j++) acc[i][j] = (f32x4){0.f, 0.f, 0.f, 0.f};

    const int rowA = tid >> 2, colA = (tid & 3) * 8;
    for (int k0 = 0; k0 < K; k0 += 32) {
        gload16(A + (size_t)(m0 + rowA) * K + k0 + colA, &As[tid * 8]);
        gload16(A + (size_t)(m0 + 64 + rowA) * K + k0 + colA, &As[2048 + tid * 8]);
        gload16(Bm + (size_t)(n0 + rowA) * K + k0 + colA, &Bs[tid * 8]);
        gload16(Bm + (size_t)(n0 + 64 + rowA) * K + k0 + colA, &Bs[2048 + tid * 8]);
        __syncthreads();
        f16x8 af[4], bfr[4];
        #pragma unroll
        for (int i = 0; i < 4; i++)
            af[i] = *(const f16x8*)&As[(wm * 64 + i * 16 + l15) * 32 + kg * 8];
        #pragma unroll
        for (int i = 0; i < 4; i++)
            bfr[i] = *(const f16x8*)&Bs[(wn * 64 + i * 16 + l15) * 32 + kg * 8];
        #pragma unroll
        for (int mi = 0; mi < 4; mi++)
            #pragma unroll
            for (int ni = 0; ni < 4; ni++)
                acc[mi][ni] = mfma16(af[mi], bfr[ni], acc[mi][ni]);
        __syncthreads();
    }

    // epilogue: C/D layout col = lane&15, row = (lane>>4)*4 + r
    #pragma unroll
    for (int mi = 0; mi < 4; mi++) {
        #pragma unroll
        for (int ni = 0; ni < 4; ni++) {
            #pragma unroll
            for (int r = 0; r < 4; r++) {
                int row = m0 + wm * 64 + mi * 16 + kg * 4 + r;
                int col = n0 + wn * 64 + ni * 16 + l15;
                float v = acc[mi][ni][r];
                if constexpr (MODE == 0) {
                    v += bias[col];
                    u16 hv = f2h(v);
                    if (n0 < 256) {
                        oq[(size_t)row * CI + col] = hv;
                    } else if (n0 < 512) {
                        okk[(size_t)row * CI + (col - 256)] = hv;
                    } else {
                        int d = col - 512;
                        int bi = row >> 12, key = row & (NN - 1);
                        ov[((size_t)bi * CI + d) * NN + key] = hv;  // V^T
                    }
                } else {
                    size_t o = (size_t)row * 512 + col;
                    of[o] = xres[o] + v + bias[col];
                }
            }
        }
    }
}

// ============ flash attention ============
// grid 256 = 4 batches x 64 q-tiles of 64 rows; block 256 = 4 waves x 16 q-rows
// LDS (double-buffered): Ks 2x[64][256] swz (64KB) | Vt 2x[256][64] swz (64KB) | Ps [4][16][72] (9KB)
#define ATTN_LDS (2 * 64 * 256 * 2 + 2 * 256 * 64 * 2 + 4 * 16 * 72 * 2)  // 140288

// stage K tile (64 keys x 256 d), pre-swizzled source, linear LDS dest
DEV void stageK(const u16* __restrict__ Kg, size_t kvbase, int kv0, u16* Ks, int tid) {
    const int chunk = tid & 31, rb = tid >> 5;
    #pragma unroll
    for (int i = 0; i < 8; i++) {
        int row = i * 8 + rb;
        int sc = chunk ^ (row & 7);
        gload16(Kg + kvbase + (size_t)(kv0 + row) * CI + sc * 8,
                &Ks[row * 256 + chunk * 8]);
    }
}

// stage V^T tile (256 d x 64 keys), pre-swizzled source, linear LDS dest
DEV void stageV(const u16* __restrict__ Vtg, size_t vbase, int kv0, u16* Vt, int tid) {
    const int c = tid & 7, db = tid >> 3;
    #pragma unroll
    for (int i = 0; i < 8; i++) {
        int d = i * 32 + db;
        int sc = c ^ (d & 7);
        gload16(Vtg + vbase + (size_t)d * NN + kv0 + sc * 8,
                &Vt[d * 64 + c * 8]);
    }
}

__global__ __launch_bounds__(256) void attn_kernel(
    const u16* __restrict__ Qg, const u16* __restrict__ Kg,
    const u16* __restrict__ Vtg, u16* __restrict__ Yg) {
    extern __shared__ u16 smem[];

    const int tid = threadIdx.x, lane = tid & 63, wv = tid >> 6;
    const int l15 = lane & 15, kg = lane >> 4;
    const int b = blockIdx.x >> 6, qt = blockIdx.x & 63;
    const size_t kvbase = (size_t)b * NN * CI;
    const size_t vbase = (size_t)b * CI * NN;

    // Q fragments in registers: row = wv*16 + l15, k = kk*32 + kg*8 + j
    f16x8 qf[8];
    {
        const u16* qp = Qg + ((size_t)b * NN + qt * 64 + wv * 16 + l15) * CI + kg * 8;
        #pragma unroll
        for (int kk = 0; kk < 8; kk++) qf[kk] = *(const f16x8*)(qp + kk * 32);
    }

    f32x4 acc[16];
    #pragma unroll
    for (int i = 0; i < 16; i++) acc[i] = (f32x4){0.f, 0.f, 0.f, 0.f};
    float mrow[4], lrow[4];
    #pragma unroll
    for (int r = 0; r < 4; r++) { mrow[r] = -1e30f; lrow[r] = 0.f; }

    u16* Psw = smem + 65536 + wv * 1152;

    // prologue: stage tile 0
    stageK(Kg, kvbase, 0, smem, tid);
    stageV(Vtg, vbase, 0, smem + 32768, tid);
    __syncthreads();  // drains vmcnt

    for (int it = 0; it < NN / 64; ++it) {
        const int cur = (it & 1) ? 16384 : 0;
        const u16* Ks = smem + cur;
        const u16* Vt = smem + 32768 + cur;
        // prefetch next tile into the other buffer (overlaps with compute below)
        if (it + 1 < NN / 64) {
            const int nxt = cur ^ 16384;
            stageK(Kg, kvbase, (it + 1) * 64, smem + nxt, tid);
            stageV(Vtg, vbase, (it + 1) * 64, smem + 32768 + nxt, tid);
        }

        // ---- S = Q K^T (16 rows x 64 keys per wave)
        f32x4 s[4];
        #pragma unroll
        for (int nt = 0; nt < 4; nt++) s[nt] = (f32x4){0.f, 0.f, 0.f, 0.f};
        __builtin_amdgcn_s_setprio(1);
        #pragma unroll
        for (int kk = 0; kk < 8; kk++) {
            #pragma unroll
            for (int nt = 0; nt < 4; nt++) {
                int krow = nt * 16 + l15;
                f16x8 bk = *(const f16x8*)&Ks[krow * 256 + (((kk * 4 + kg) ^ (krow & 7)) << 3)];
                s[nt] = mfma16(qf[kk], bk, s[nt]);
            }
        }
        __builtin_amdgcn_s_setprio(0);

        // ---- online softmax (rows kg*4+r; cols across the 16 lanes of the group)
        float scl[4];
        #pragma unroll
        for (int r = 0; r < 4; r++) {
            float mx = fmaxf(fmaxf(s[0][r], s[1][r]), fmaxf(s[2][r], s[3][r]));
            mx = fmaxf(mx, __shfl_xor(mx, 1));
            mx = fmaxf(mx, __shfl_xor(mx, 2));
            mx = fmaxf(mx, __shfl_xor(mx, 4));
            mx = fmaxf(mx, __shfl_xor(mx, 8));
            float mnew = fmaxf(mrow[r], mx);
            scl[r] = __expf(mrow[r] - mnew);
            mrow[r] = mnew;
        }
        float rs[4] = {0.f, 0.f, 0.f, 0.f};
        #pragma unroll
        for (int nt = 0; nt < 4; nt++)
            #pragma unroll
            for (int r = 0; r < 4; r++) {
                float p = __expf(s[nt][r] - mrow[r]);
                s[nt][r] = p;
                rs[r] += p;
            }
        #pragma unroll
        for (int r = 0; r < 4; r++) {
            rs[r] += __shfl_xor(rs[r], 1);
            rs[r] += __shfl_xor(rs[r], 2);
            rs[r] += __shfl_xor(rs[r], 4);
            rs[r] += __shfl_xor(rs[r], 8);
            lrow[r] = lrow[r] * scl[r] + rs[r];
        }
        #pragma unroll
        for (int i = 0; i < 16; i++)
            #pragma unroll
            for (int r = 0; r < 4; r++) acc[i][r] *= scl[r];

        // ---- P -> LDS (fp16), layout [qrow][key] stride 72
        #pragma unroll
        for (int nt = 0; nt < 4; nt++)
            #pragma unroll
            for (int r = 0; r < 4; r++)
                Psw[(kg * 4 + r) * 72 + nt * 16 + l15] = f2h(s[nt][r]);

        // ---- PV: acc += P(16x64) * V(64x256)
        __builtin_amdgcn_s_setprio(1);
        #pragma unroll
        for (int kk2 = 0; kk2 < 2; kk2++) {
            f16x8 pa = *(const f16x8*)&Psw[l15 * 72 + kk2 * 32 + kg * 8];
            #pragma unroll
            for (int dt = 0; dt < 16; dt++) {
                int d = dt * 16 + l15;
                f16x8 bv = *(const f16x8*)&Vt[d * 64 + (((kk2 * 4 + kg) ^ (d & 7)) << 3)];
                acc[dt] = mfma16(pa, bv, acc[dt]);
            }
        }
        __builtin_amdgcn_s_setprio(0);

        __syncthreads();  // drains prefetch vmcnt + LDS; flips buffers
    }

    // ---- write Y (fp16)
    const size_t orow0 = (size_t)b * NN + qt * 64 + wv * 16;
    #pragma unroll
    for (int dt = 0; dt < 16; dt++)
        #pragma unroll
        for (int r = 0; r < 4; r++) {
            float o = acc[dt][r] / lrow[r];
            Yg[(orow0 + kg * 4 + r) * CI + dt * 16 + l15] = f2h(o);
        }
}

// ============ launcher ============
extern "C" void kernel_launch(void* const* d_in, const int* in_sizes, int n_in,
                              void* d_out, int out_size, void* d_ws, size_t ws_size,
                              hipStream_t stream) {
    (void)in_sizes; (void)n_in; (void)out_size; (void)ws_size;
    const float* x     = (const float*)d_in[0];
    const float* gamma = (const float*)d_in[1];
    const float* beta  = (const float*)d_in[2];
    const float* thw   = (const float*)d_in[3];
    const float* thb   = (const float*)d_in[4];
    const float* phw   = (const float*)d_in[5];
    const float* phb   = (const float*)d_in[6];
    const float* gw    = (const float*)d_in[7];
    const float* gb    = (const float*)d_in[8];
    const float* ww    = (const float*)d_in[9];
    const float* wb    = (const float*)d_in[10];

    char* ws = (char*)d_ws;
    u16* feat  = (u16*)(ws + OFF_FEAT);
    u16* qb    = (u16*)(ws + OFF_Q);
    u16* kb    = (u16*)(ws + OFF_K);
    u16* vtb   = (u16*)(ws + OFF_V);
    u16* yb    = (u16*)(ws + OFF_Y);
    u16* wqkv  = (u16*)(ws + OFF_WQKV);
    u16* wo    = (u16*)(ws + OFF_WO);
    float* bqkv = (float*)(ws + OFF_BQKV);
    float* part = (float*)(ws + OFF_PART);
    float* ss   = (float*)(ws + OFF_SS);
    float* out  = (float*)d_out;

    (void)hipFuncSetAttribute((const void*)attn_kernel,
                              hipFuncAttributeMaxDynamicSharedMemorySize, ATTN_LDS);

    bn_partial<<<128, 512, 0, stream>>>(x, part);
    bn_final<<<1, 512, 0, stream>>>(part, gamma, beta, ss);
    cvt_weights<<<2048, 256, 0, stream>>>(thw, phw, gw, thb, phb, gb, ww, wqkv, wo, bqkv);
    feat_kernel<<<2048, 256, 0, stream>>>(x, ss, feat);
    gemm_bt<0><<<dim3(128, 6), 256, 0, stream>>>(feat, wqkv, 512, bqkv, nullptr,
                                                 qb, kb, vtb, nullptr);
    attn_kernel<<<256, 256, ATTN_LDS, stream>>>(qb, kb, vtb, yb);
    gemm_bt<1><<<dim3(128, 4), 256, 0, stream>>>(yb, wo, 256, wb, x,
                                                 nullptr, nullptr, nullptr, out);
}

// Round 5
// 227.564 us; speedup vs baseline: 1.4484x; 1.0870x over previous
//
#include <hip/hip_runtime.h>

typedef unsigned short u16;
typedef __attribute__((ext_vector_type(4))) float f32x4;
typedef __attribute__((ext_vector_type(8))) _Float16 f16x8;
typedef __attribute__((ext_vector_type(8))) unsigned short u16x8;
typedef __attribute__((ext_vector_type(4))) unsigned short u16x4;

#define DEV __device__ __forceinline__

// ---------- helpers ----------
DEV u16 f2h(float f) {
    _Float16 h = (_Float16)f;
    u16 r;
    __builtin_memcpy(&r, &h, 2);
    return r;
}
DEV float h2f(u16 u) {
    _Float16 h;
    __builtin_memcpy(&h, &u, 2);
    return (float)h;
}

DEV f32x4 mfma16(f16x8 a, f16x8 b, f32x4 c) {
    return __builtin_amdgcn_mfma_f32_16x16x32_f16(a, b, c, 0, 0, 0);
}

DEV void gload16(const void* g, void* l) {
    __builtin_amdgcn_global_load_lds(
        (const __attribute__((address_space(1))) void*)g,
        (__attribute__((address_space(3))) void*)l, 16, 0, 0);
}

// ---------- problem constants ----------
#define BB 4
#define NN 4096
#define CC 512
#define CI 256
#define RR (BB * NN)  // 16384

// ---------- workspace layout (bytes) ----------
#define OFF_FEAT 0u                     // 16 MB: feat, later reused for attn partial O (2x8MB)
#define OFF_Q    16777216u
#define OFF_K    25165824u
#define OFF_V    33554432u              // V^T layout [b][d][key]
#define OFF_Y    41943040u
#define OFF_WQKV 50331648u
#define OFF_WO   51118080u
#define OFF_BQKV 51380224u
#define OFF_PART 51383296u              // 512KB: bn partials, later reused for attn m/l (256KB)
#define OFF_SS   51907584u

// ============ BN stats ============
__global__ void bn_partial(const float* __restrict__ x, float* __restrict__ part) {
    const int c = threadIdx.x;
    const int blk = blockIdx.x;
    const float* xp = x + (size_t)blk * 128 * CC + c;
    float s = 0.f, q = 0.f;
    for (int r = 0; r < 128; r++) {
        float v = xp[(size_t)r * CC];
        s += v; q += v * v;
    }
    part[blk * 1024 + c] = s;
    part[blk * 1024 + 512 + c] = q;
}

__global__ void bn_final(const float* __restrict__ part,
                         const float* __restrict__ gamma, const float* __restrict__ beta,
                         float* __restrict__ ss) {
    const int c = threadIdx.x;
    float s = 0.f, q = 0.f;
    for (int i = 0; i < 128; i++) {
        s += part[i * 1024 + c];
        q += part[i * 1024 + 512 + c];
    }
    float m = s * (1.0f / (float)RR);
    float var = q * (1.0f / (float)RR) - m * m;
    float istd = rsqrtf(var + 1e-5f);
    float g = gamma[c] * istd;
    ss[c] = g;
    ss[512 + c] = beta[c] - m * g;
}

// ============ weight conversion ============
__global__ void cvt_weights(const float* __restrict__ thw, const float* __restrict__ phw,
                            const float* __restrict__ gw,
                            const float* __restrict__ thb, const float* __restrict__ phb,
                            const float* __restrict__ gb,
                            const float* __restrict__ ww,
                            u16* __restrict__ wqkv, u16* __restrict__ wo,
                            float* __restrict__ bqkv) {
    const int idx = blockIdx.x * 256 + threadIdx.x;
    if (idx < 768 * 512) {
        int row = idx >> 9, col = idx & 511;
        float v = (row < 256) ? thw[row * 512 + col]
                : (row < 512) ? phw[(row - 256) * 512 + col]
                              : gw[(row - 512) * 512 + col];
        wqkv[idx] = f2h(v);
    } else if (idx < 768 * 512 + 512 * 256) {
        int j = idx - 768 * 512;
        wo[j] = f2h(ww[j]);
    }
    if (idx < 768) {
        bqkv[idx] = (idx < 256) ? thb[idx] : (idx < 512) ? phb[idx - 256] : gb[idx - 512];
    }
}

// ============ BN apply + ReLU -> fp16 ============
__global__ void feat_kernel(const float* __restrict__ x, const float* __restrict__ ss,
                            u16* __restrict__ feat) {
    const int total = RR * CC / 4;
    for (int idx = blockIdx.x * blockDim.x + threadIdx.x; idx < total;
         idx += gridDim.x * blockDim.x) {
        f32x4 xv = ((const f32x4*)x)[idx];
        int c4 = idx & 127;
        f32x4 sc = ((const f32x4*)ss)[c4];
        f32x4 sh = ((const f32x4*)(ss + 512))[c4];
        u16x4 o;
        #pragma unroll
        for (int e = 0; e < 4; e++) {
            float f = fmaxf(xv[e] * sc[e] + sh[e], 0.f);
            o[e] = f2h(f);
        }
        ((u16x4*)feat)[idx] = o;
    }
}

// ============ GEMM ============
template <int MODE>
__global__ __launch_bounds__(256) void gemm_bt(
    const u16* __restrict__ A, const u16* __restrict__ Bm, int K,
    const float* __restrict__ bias, const float* __restrict__ xres,
    u16* __restrict__ oq, u16* __restrict__ okk, u16* __restrict__ ov,
    float* __restrict__ of) {
    __shared__ u16 As[128 * 32];
    __shared__ u16 Bs[128 * 32];
    const int tid = threadIdx.x;
    const int lane = tid & 63;
    const int l15 = lane & 15, kg = lane >> 4;
    const int wv = tid >> 6;
    const int wm = wv >> 1, wn = wv & 1;
    const int m0 = blockIdx.x * 128, n0 = blockIdx.y * 128;

    f32x4 acc[4][4];
    #pragma unroll
    for (int i = 0; i < 4; i++)
        #pragma unroll
        for (int j = 0; j < 4; j++) acc[i][j] = (f32x4){0.f, 0.f, 0.f, 0.f};

    const int rowA = tid >> 2, colA = (tid & 3) * 8;
    for (int k0 = 0; k0 < K; k0 += 32) {
        gload16(A + (size_t)(m0 + rowA) * K + k0 + colA, &As[tid * 8]);
        gload16(A + (size_t)(m0 + 64 + rowA) * K + k0 + colA, &As[2048 + tid * 8]);
        gload16(Bm + (size_t)(n0 + rowA) * K + k0 + colA, &Bs[tid * 8]);
        gload16(Bm + (size_t)(n0 + 64 + rowA) * K + k0 + colA, &Bs[2048 + tid * 8]);
        __syncthreads();
        f16x8 af[4], bfr[4];
        #pragma unroll
        for (int i = 0; i < 4; i++)
            af[i] = *(const f16x8*)&As[(wm * 64 + i * 16 + l15) * 32 + kg * 8];
        #pragma unroll
        for (int i = 0; i < 4; i++)
            bfr[i] = *(const f16x8*)&Bs[(wn * 64 + i * 16 + l15) * 32 + kg * 8];
        #pragma unroll
        for (int mi = 0; mi < 4; mi++)
            #pragma unroll
            for (int ni = 0; ni < 4; ni++)
                acc[mi][ni] = mfma16(af[mi], bfr[ni], acc[mi][ni]);
        __syncthreads();
    }

    #pragma unroll
    for (int mi = 0; mi < 4; mi++) {
        #pragma unroll
        for (int ni = 0; ni < 4; ni++) {
            #pragma unroll
            for (int r = 0; r < 4; r++) {
                int row = m0 + wm * 64 + mi * 16 + kg * 4 + r;
                int col = n0 + wn * 64 + ni * 16 + l15;
                float v = acc[mi][ni][r];
                if constexpr (MODE == 0) {
                    v += bias[col];
                    u16 hv = f2h(v);
                    if (n0 < 256) {
                        oq[(size_t)row * CI + col] = hv;
                    } else if (n0 < 512) {
                        okk[(size_t)row * CI + (col - 256)] = hv;
                    } else {
                        int d = col - 512;
                        int bi = row >> 12, key = row & (NN - 1);
                        ov[((size_t)bi * CI + d) * NN + key] = hv;  // V^T
                    }
                } else {
                    size_t o = (size_t)row * 512 + col;
                    of[o] = xres[o] + v + bias[col];
                }
            }
        }
    }
}

// ============ flash attention, split-KV ============
// grid 512 = 4 batches x 64 q-tiles x 2 key-splits; block 256 = 4 waves x 16 q-rows
// LDS: Ks 2x[32][256] swz | Vt 2x[256][32] swz | Ps [4][16][40]  = 70656 B -> 2 blocks/CU
#define KVB 32
#define ATTN_LDS (2 * KVB * 256 * 2 + 2 * 256 * KVB * 2 + 4 * 16 * 40 * 2)  // 70656

DEV void stageK32(const u16* __restrict__ Kg, size_t kvbase, int kv0, u16* Ks, int tid) {
    const int chunk = tid & 31, rb = tid >> 5;  // dest = wavebase + lane*8 elems (required)
    #pragma unroll
    for (int i = 0; i < 4; i++) {
        int row = i * 8 + rb;
        int sc = chunk ^ (row & 7);
        gload16(Kg + kvbase + (size_t)(kv0 + row) * CI + sc * 8,
                &Ks[row * 256 + chunk * 8]);
    }
}

DEV void stageV32(const u16* __restrict__ Vtg, size_t vbase, int kv0, u16* Vt, int tid) {
    const int c = tid & 3, db = tid >> 2;  // dest = wavebase + lane*8 elems (required)
    #pragma unroll
    for (int i = 0; i < 4; i++) {
        int d = i * 64 + db;
        int sc = c ^ ((d >> 1) & 3);
        gload16(Vtg + vbase + (size_t)d * NN + kv0 + sc * 8,
                &Vt[d * KVB + c * 8]);
    }
}

__global__ __launch_bounds__(256) void attn_kernel(
    const u16* __restrict__ Qg, const u16* __restrict__ Kg,
    const u16* __restrict__ Vtg, u16* __restrict__ po, float* __restrict__ ml) {
    extern __shared__ u16 smem[];

    const int tid = threadIdx.x, lane = tid & 63, wv = tid >> 6;
    const int l15 = lane & 15, kg = lane >> 4;
    // XCD-aware swizzle (512 % 8 == 0): each XCD gets one batch-half's K/V (2MB < 4MB L2)
    const int sid = (blockIdx.x & 7) * 64 + (blockIdx.x >> 3);
    const int qt = sid & 63;
    const int b = (sid >> 6) & 3;
    const int sp = sid >> 8;             // key split 0/1
    const int kvoff = sp * (NN / 2);
    const size_t kvbase = (size_t)b * NN * CI;
    const size_t vbase = (size_t)b * CI * NN;

    // Q fragments: row = wv*16 + l15, k = kk*32 + kg*8 + j
    f16x8 qf[8];
    {
        const u16* qp = Qg + ((size_t)b * NN + qt * 64 + wv * 16 + l15) * CI + kg * 8;
        #pragma unroll
        for (int kk = 0; kk < 8; kk++) qf[kk] = *(const f16x8*)(qp + kk * 32);
    }

    f32x4 acc[16];
    #pragma unroll
    for (int i = 0; i < 16; i++) acc[i] = (f32x4){0.f, 0.f, 0.f, 0.f};
    float mrow[4], lrow[4];
    #pragma unroll
    for (int r = 0; r < 4; r++) { mrow[r] = -1e30f; lrow[r] = 0.f; }

    u16* Psw = smem + 32768 + wv * 640;

    stageK32(Kg, kvbase, kvoff, smem, tid);
    stageV32(Vtg, vbase, kvoff, smem + 16384, tid);
    __syncthreads();

    for (int it = 0; it < (NN / 2) / KVB; ++it) {
        const int cur = (it & 1) * 8192;
        const u16* Ks = smem + cur;
        const u16* Vt = smem + 16384 + cur;
        if (it + 1 < (NN / 2) / KVB) {
            const int nxt = cur ^ 8192;
            stageK32(Kg, kvbase, kvoff + (it + 1) * KVB, smem + nxt, tid);
            stageV32(Vtg, vbase, kvoff + (it + 1) * KVB, smem + 16384 + nxt, tid);
        }

        // ---- S = Q K^T (16 rows x 32 keys per wave)
        f32x4 s[2];
        #pragma unroll
        for (int nt = 0; nt < 2; nt++) s[nt] = (f32x4){0.f, 0.f, 0.f, 0.f};
        __builtin_amdgcn_s_setprio(1);
        #pragma unroll
        for (int kk = 0; kk < 8; kk++) {
            #pragma unroll
            for (int nt = 0; nt < 2; nt++) {
                int krow = nt * 16 + l15;
                f16x8 bk = *(const f16x8*)&Ks[krow * 256 + (((kk * 4 + kg) ^ (krow & 7)) << 3)];
                s[nt] = mfma16(qf[kk], bk, s[nt]);
            }
        }
        __builtin_amdgcn_s_setprio(0);

        // ---- online softmax with defer-max (THR=8)
        float tmx[4];
        float need = -1e30f;
        #pragma unroll
        for (int r = 0; r < 4; r++) {
            float mx = fmaxf(s[0][r], s[1][r]);
            mx = fmaxf(mx, __shfl_xor(mx, 1));
            mx = fmaxf(mx, __shfl_xor(mx, 2));
            mx = fmaxf(mx, __shfl_xor(mx, 4));
            mx = fmaxf(mx, __shfl_xor(mx, 8));
            tmx[r] = mx;
            need = fmaxf(need, mx - mrow[r]);
        }
        if (!__all(need <= 8.f)) {
            #pragma unroll
            for (int r = 0; r < 4; r++) {
                float mnew = fmaxf(mrow[r], tmx[r]);
                float scl = __expf(mrow[r] - mnew);
                mrow[r] = mnew;
                lrow[r] *= scl;
                #pragma unroll
                for (int i = 0; i < 16; i++) acc[i][r] *= scl;
            }
        }
        float rs[4] = {0.f, 0.f, 0.f, 0.f};
        #pragma unroll
        for (int nt = 0; nt < 2; nt++)
            #pragma unroll
            for (int r = 0; r < 4; r++) {
                float p = __expf(s[nt][r] - mrow[r]);
                s[nt][r] = p;
                rs[r] += p;
            }
        #pragma unroll
        for (int r = 0; r < 4; r++) {
            rs[r] += __shfl_xor(rs[r], 1);
            rs[r] += __shfl_xor(rs[r], 2);
            rs[r] += __shfl_xor(rs[r], 4);
            rs[r] += __shfl_xor(rs[r], 8);
            lrow[r] += rs[r];
        }

        // ---- P -> LDS, [qrow][key] stride 40
        #pragma unroll
        for (int nt = 0; nt < 2; nt++)
            #pragma unroll
            for (int r = 0; r < 4; r++)
                Psw[(kg * 4 + r) * 40 + nt * 16 + l15] = f2h(s[nt][r]);

        // ---- PV: acc += P(16x32) * V(32x256)
        __builtin_amdgcn_s_setprio(1);
        {
            f16x8 pa = *(const f16x8*)&Psw[l15 * 40 + kg * 8];
            #pragma unroll
            for (int dt = 0; dt < 16; dt++) {
                int d = dt * 16 + l15;
                f16x8 bv = *(const f16x8*)&Vt[d * KVB + ((kg ^ ((d >> 1) & 3)) << 3)];
                acc[dt] = mfma16(pa, bv, acc[dt]);
            }
        }
        __builtin_amdgcn_s_setprio(0);

        __syncthreads();
    }

    // ---- write normalized partial O (fp16) + m/l
    const int row0 = b * NN + qt * 64 + wv * 16;
    u16* pod = po + (size_t)sp * RR * CI;
    #pragma unroll
    for (int dt = 0; dt < 16; dt++)
        #pragma unroll
        for (int r = 0; r < 4; r++) {
            float o = acc[dt][r] / lrow[r];
            pod[(size_t)(row0 + kg * 4 + r) * CI + dt * 16 + l15] = f2h(o);
        }
    if (l15 == 0) {
        #pragma unroll
        for (int r = 0; r < 4; r++) {
            int row = row0 + kg * 4 + r;
            ml[row * 4 + sp * 2] = mrow[r];
            ml[row * 4 + sp * 2 + 1] = lrow[r];
        }
    }
}

// ============ combine the two KV-splits ============
__global__ void attn_combine(const u16* __restrict__ po, const float* __restrict__ ml,
                             u16* __restrict__ yb) {
    const int gid = blockIdx.x * 256 + threadIdx.x;  // RR*CI/4 threads
    const int row = gid >> 6;
    const int d0 = (gid & 63) * 4;
    f32x4 mlv = ((const f32x4*)ml)[row];
    float m = fmaxf(mlv[0], mlv[2]);
    float c0 = __expf(mlv[0] - m) * mlv[1];
    float c1 = __expf(mlv[2] - m) * mlv[3];
    float inv = 1.f / (c0 + c1);
    u16x4 a = *(const u16x4*)(po + (size_t)row * CI + d0);
    u16x4 bq = *(const u16x4*)(po + (size_t)RR * CI + (size_t)row * CI + d0);
    u16x4 o;
    #pragma unroll
    for (int e = 0; e < 4; e++)
        o[e] = f2h((c0 * h2f(a[e]) + c1 * h2f(bq[e])) * inv);
    *(u16x4*)(yb + (size_t)row * CI + d0) = o;
}

// ============ launcher ============
extern "C" void kernel_launch(void* const* d_in, const int* in_sizes, int n_in,
                              void* d_out, int out_size, void* d_ws, size_t ws_size,
                              hipStream_t stream) {
    (void)in_sizes; (void)n_in; (void)out_size; (void)ws_size;
    const float* x     = (const float*)d_in[0];
    const float* gamma = (const float*)d_in[1];
    const float* beta  = (const float*)d_in[2];
    const float* thw   = (const float*)d_in[3];
    const float* thb   = (const float*)d_in[4];
    const float* phw   = (const float*)d_in[5];
    const float* phb   = (const float*)d_in[6];
    const float* gw    = (const float*)d_in[7];
    const float* gb    = (const float*)d_in[8];
    const float* ww    = (const float*)d_in[9];
    const float* wb    = (const float*)d_in[10];

    char* ws = (char*)d_ws;
    u16* feat  = (u16*)(ws + OFF_FEAT);   // also: attn partial O (2 x 8MB fp16)
    u16* qb    = (u16*)(ws + OFF_Q);
    u16* kb    = (u16*)(ws + OFF_K);
    u16* vtb   = (u16*)(ws + OFF_V);
    u16* yb    = (u16*)(ws + OFF_Y);
    u16* wqkv  = (u16*)(ws + OFF_WQKV);
    u16* wo    = (u16*)(ws + OFF_WO);
    float* bqkv = (float*)(ws + OFF_BQKV);
    float* part = (float*)(ws + OFF_PART); // also: attn m/l (256KB)
    float* ss   = (float*)(ws + OFF_SS);
    float* out  = (float*)d_out;

    (void)hipFuncSetAttribute((const void*)attn_kernel,
                              hipFuncAttributeMaxDynamicSharedMemorySize, ATTN_LDS);

    bn_partial<<<128, 512, 0, stream>>>(x, part);
    bn_final<<<1, 512, 0, stream>>>(part, gamma, beta, ss);
    cvt_weights<<<2048, 256, 0, stream>>>(thw, phw, gw, thb, phb, gb, ww, wqkv, wo, bqkv);
    feat_kernel<<<2048, 256, 0, stream>>>(x, ss, feat);
    gemm_bt<0><<<dim3(128, 6), 256, 0, stream>>>(feat, wqkv, 512, bqkv, nullptr,
                                                 qb, kb, vtb, nullptr);
    attn_kernel<<<512, 256, ATTN_LDS, stream>>>(qb, kb, vtb, feat, part);
    attn_combine<<<RR * CI / 4 / 256, 256, 0, stream>>>(feat, part, yb);
    gemm_bt<1><<<dim3(128, 4), 256, 0, stream>>>(yb, wo, 256, wb, x,
                                                 nullptr, nullptr, nullptr, out);
}